// Round 2
// baseline (1195.150 us; speedup 1.0000x reference)
//
#include <hip/hip_runtime.h>
#include <hip/hip_bf16.h>

// GCN link-prediction, N=1M, D=16, E=5M, EL=2M.
// R2: replace atomic scatter with per-launch CSR build + pull-based gather,
// fusing finalize (+b, relu, *dinv) and the 16x16 GEMM (via 16-lane shfl)
// into the gather kernels. dinv derived from ptr[d+1]-ptr[d] (no deg pass).
// g-storage dtype selected at runtime from ws_size (fp32 if it fits, else bf16).

typedef __hip_bfloat16 bf16;

template <typename T> struct GIO;

template <> struct GIO<float> {
  static __device__ __forceinline__ float load1(const float* p) { return *p; }
  static __device__ __forceinline__ void store1(float* p, float v) { *p = v; }
  static __device__ __forceinline__ void load16(const float* p, float* h) {
    const float4* q = (const float4*)p;
    float4 a = q[0], b = q[1], c = q[2], d = q[3];
    h[0]=a.x;h[1]=a.y;h[2]=a.z;h[3]=a.w; h[4]=b.x;h[5]=b.y;h[6]=b.z;h[7]=b.w;
    h[8]=c.x;h[9]=c.y;h[10]=c.z;h[11]=c.w; h[12]=d.x;h[13]=d.y;h[14]=d.z;h[15]=d.w;
  }
  static __device__ __forceinline__ void store16(float* p, const float* h) {
    float4* q = (float4*)p;
    q[0]=make_float4(h[0],h[1],h[2],h[3]);
    q[1]=make_float4(h[4],h[5],h[6],h[7]);
    q[2]=make_float4(h[8],h[9],h[10],h[11]);
    q[3]=make_float4(h[12],h[13],h[14],h[15]);
  }
};

template <> struct GIO<bf16> {
  static __device__ __forceinline__ float load1(const bf16* p) { return __bfloat162float(*p); }
  static __device__ __forceinline__ void store1(bf16* p, float v) { *p = __float2bfloat16(v); }
  static __device__ __forceinline__ void load16(const bf16* p, float* h) {
    const uint4* q = (const uint4*)p;
    uint4 a = q[0], b = q[1];
    unsigned u[8] = {a.x,a.y,a.z,a.w,b.x,b.y,b.z,b.w};
#pragma unroll
    for (int j = 0; j < 8; ++j) {
      unsigned short lo = (unsigned short)(u[j] & 0xffffu);
      unsigned short hi = (unsigned short)(u[j] >> 16);
      bf16 bl, bh;
      __builtin_memcpy(&bl, &lo, 2); __builtin_memcpy(&bh, &hi, 2);
      h[2*j]   = __bfloat162float(bl);
      h[2*j+1] = __bfloat162float(bh);
    }
  }
  static __device__ __forceinline__ void store16(bf16* p, const float* h) {
    unsigned short t[16];
#pragma unroll
    for (int j = 0; j < 16; ++j) {
      bf16 b = __float2bfloat16(h[j]);
      __builtin_memcpy(&t[j], &b, 2);
    }
    uint4* q = (uint4*)p;
    uint4 r0, r1;
    __builtin_memcpy(&r0, &t[0], 16);
    __builtin_memcpy(&r1, &t[8], 16);
    q[0] = r0; q[1] = r1;
  }
};

// ---- CSR build ----------------------------------------------------------

__global__ __launch_bounds__(256) void hist_kernel(
    const int* __restrict__ dst, int* __restrict__ cnt, int E) {
  int e = blockIdx.x * 256 + threadIdx.x;
  if (e < E) atomicAdd(&cnt[dst[e]], 1);
}

// block = 256 threads x 4 elems = 1024 elems/block; local exclusive scan
__global__ __launch_bounds__(256) void scan1_kernel(
    const int* __restrict__ cnt, int* __restrict__ ptr,
    int* __restrict__ bsum, int n) {
  __shared__ int s[256];
  int t = threadIdx.x;
  int base = blockIdx.x * 1024 + t * 4;
  int v0 = 0, v1 = 0, v2 = 0, v3 = 0;
  if (base + 3 < n) {
    int4 q = *(const int4*)(cnt + base);
    v0 = q.x; v1 = q.y; v2 = q.z; v3 = q.w;
  } else {
    if (base     < n) v0 = cnt[base];
    if (base + 1 < n) v1 = cnt[base + 1];
    if (base + 2 < n) v2 = cnt[base + 2];
    if (base + 3 < n) v3 = cnt[base + 3];
  }
  s[t] = v0 + v1 + v2 + v3;
  __syncthreads();
  for (int off = 1; off < 256; off <<= 1) {
    int x = (t >= off) ? s[t - off] : 0;
    __syncthreads();
    s[t] += x;
    __syncthreads();
  }
  if (t == 255) bsum[blockIdx.x] = s[255];
  int e = (t == 0) ? 0 : s[t - 1];
  if (base     < n) ptr[base]     = e; e += v0;
  if (base + 1 < n) ptr[base + 1] = e; e += v1;
  if (base + 2 < n) ptr[base + 2] = e; e += v2;
  if (base + 3 < n) ptr[base + 3] = e;
}

// single-block exclusive scan of block sums (loops for nb > 1024)
__global__ __launch_bounds__(1024) void scan2_kernel(int* __restrict__ bsum, int nb) {
  __shared__ int s[1024];
  int t = threadIdx.x;
  int carry = 0;
  for (int base = 0; base < nb; base += 1024) {
    int i = base + t;
    int v = (i < nb) ? bsum[i] : 0;
    s[t] = v;
    __syncthreads();
    for (int off = 1; off < 1024; off <<= 1) {
      int x = (t >= off) ? s[t - off] : 0;
      __syncthreads();
      s[t] += x;
      __syncthreads();
    }
    int excl = carry + ((t == 0) ? 0 : s[t - 1]);
    if (i < nb) bsum[i] = excl;
    carry += s[1023];
    __syncthreads();
  }
}

__global__ __launch_bounds__(256) void addback_kernel(
    int* __restrict__ ptr, int* __restrict__ next,
    const int* __restrict__ bsum, int n, int E) {
  int i = blockIdx.x * 256 + threadIdx.x;
  if (i < n) {
    int p = ptr[i] + bsum[i >> 10];
    ptr[i] = p;
    next[i] = p;
  }
  if (i == 0) ptr[n] = E;
}

__global__ __launch_bounds__(256) void fill_kernel(
    const int* __restrict__ src, const int* __restrict__ dst,
    int* __restrict__ next, int* __restrict__ srt, int E) {
  int e = blockIdx.x * 256 + threadIdx.x;
  if (e >= E) return;
  int slot = atomicAdd(&next[dst[e]], 1);
  srt[slot] = src[e];
}

// ---- dense per-node kernels --------------------------------------------

// g[i,:] = (embed[x[i],:] @ W1) * dinv[i]
template <typename T>
__global__ __launch_bounds__(256) void embed_mm_kernel(
    const int* __restrict__ x, const float* __restrict__ embed,
    const float* __restrict__ W, const int* __restrict__ ptr,
    T* __restrict__ g, int n) {
  __shared__ float Ws[256];
  Ws[threadIdx.x] = W[threadIdx.x];
  __syncthreads();
  int i = blockIdx.x * 256 + threadIdx.x;
  if (i >= n) return;
  float dv = rsqrtf((float)(ptr[i + 1] - ptr[i]) + 1.0f);
  int row = x[i];
  float h[16];
  GIO<float>::load16(embed + (size_t)row * 16, h);
  float o[16];
#pragma unroll
  for (int j = 0; j < 16; ++j) o[j] = 0.f;
#pragma unroll
  for (int k = 0; k < 16; ++k) {
    float hk = h[k];
#pragma unroll
    for (int j = 0; j < 16; ++j) o[j] = fmaf(hk, Ws[k * 16 + j], o[j]);
  }
#pragma unroll
  for (int j = 0; j < 16; ++j) o[j] *= dv;
  GIO<T>::store16(g + (size_t)i * 16, o);
}

// 16 lanes per node: acc = g1[d] + sum g1[srt[j]]; h = relu(dv*acc + b1);
// g2[d] = (h @ W2) * dv   (GEMM across the 16-lane group via shfl)
template <typename T>
__global__ __launch_bounds__(256) void gather_mm_kernel(
    const int* __restrict__ ptr, const int* __restrict__ srt,
    const T* __restrict__ g1, const float* __restrict__ W,
    const float* __restrict__ bias, T* __restrict__ g2, int n) {
  __shared__ float Ws[256];
  __shared__ float bs[16];
  Ws[threadIdx.x] = W[threadIdx.x];
  if (threadIdx.x < 16) bs[threadIdx.x] = bias[threadIdx.x];
  __syncthreads();
  int t = blockIdx.x * 256 + threadIdx.x;
  int d = t >> 4;
  if (d >= n) return;
  int f = t & 15;
  int p0 = ptr[d], p1 = ptr[d + 1];
  float dv = rsqrtf((float)(p1 - p0) + 1.0f);
  float acc = GIO<T>::load1(g1 + (size_t)d * 16 + f);
  for (int j = p0; j < p1; ++j) {
    int s = srt[j];
    acc += GIO<T>::load1(g1 + (size_t)s * 16 + f);
  }
  float h = fmaxf(fmaf(dv, acc, bs[f]), 0.f);
  float o = 0.f;
#pragma unroll
  for (int k = 0; k < 16; ++k) o = fmaf(__shfl(h, k, 16), Ws[k * 16 + f], o);
  GIO<T>::store1(g2 + (size_t)d * 16 + f, o * dv);
}

// z[d] = dv * (g2[d] + sum g2[srt[j]]) + b2
template <typename T>
__global__ __launch_bounds__(256) void gather_fin_kernel(
    const int* __restrict__ ptr, const int* __restrict__ srt,
    const T* __restrict__ g2, const float* __restrict__ bias,
    T* __restrict__ z, int n) {
  __shared__ float bs[16];
  if (threadIdx.x < 16) bs[threadIdx.x] = bias[threadIdx.x];
  __syncthreads();
  int t = blockIdx.x * 256 + threadIdx.x;
  int d = t >> 4;
  if (d >= n) return;
  int f = t & 15;
  int p0 = ptr[d], p1 = ptr[d + 1];
  float dv = rsqrtf((float)(p1 - p0) + 1.0f);
  float acc = GIO<T>::load1(g2 + (size_t)d * 16 + f);
  for (int j = p0; j < p1; ++j) {
    int s = srt[j];
    acc += GIO<T>::load1(g2 + (size_t)s * 16 + f);
  }
  GIO<T>::store1(z + (size_t)d * 16 + f, fmaf(dv, acc, bs[f]));
}

// out[e] = [z[a], z[b]] . fc_w + fc_b
template <typename T>
__global__ __launch_bounds__(256) void predict_kernel(
    const int* __restrict__ eli, const T* __restrict__ z,
    const float* __restrict__ fcw, const float* __restrict__ fcb,
    float* __restrict__ out, int EL) {
  __shared__ float w[32];
  __shared__ float bb;
  if (threadIdx.x < 32) w[threadIdx.x] = fcw[threadIdx.x];
  if (threadIdx.x == 0) bb = fcb[0];
  __syncthreads();
  int e = blockIdx.x * 256 + threadIdx.x;
  if (e >= EL) return;
  int a = eli[e], b = eli[EL + e];
  float za[16], zb[16];
  GIO<T>::load16(z + (size_t)a * 16, za);
  GIO<T>::load16(z + (size_t)b * 16, zb);
  float s = bb;
#pragma unroll
  for (int j = 0; j < 16; ++j) s = fmaf(za[j], w[j], s);
#pragma unroll
  for (int j = 0; j < 16; ++j) s = fmaf(zb[j], w[16 + j], s);
  out[e] = s;
}

static inline int cdiv(long long a, long long b) { return (int)((a + b - 1) / b); }

template <typename T>
static void run_pipeline(const int* x, const int* src, const int* dst,
                         const int* eli, const float* embed,
                         const float* W1, const float* b1,
                         const float* W2, const float* b2,
                         const float* fcw, const float* fcb, float* out,
                         int N, int E, int EL,
                         int* ptr, int* srt, T* bufA, T* bufB,
                         hipStream_t stream) {
  // scratch aliased into bufB (dead until gather_mm writes it)
  char* bB = (char*)bufB;
  size_t ptrB = ((size_t)(N + 1) * 4 + 255) & ~(size_t)255;
  int* cnt  = (int*)bB;
  int* next = (int*)(bB + ptrB);
  int* bsum = (int*)(bB + 2 * ptrB);

  const int B = 256;
  int nb1 = cdiv(N, 1024);

  hipMemsetAsync(cnt, 0, (size_t)N * 4, stream);
  hist_kernel<<<cdiv(E, B), B, 0, stream>>>(dst, cnt, E);
  scan1_kernel<<<nb1, B, 0, stream>>>(cnt, ptr, bsum, N);
  scan2_kernel<<<1, 1024, 0, stream>>>(bsum, nb1);
  addback_kernel<<<cdiv(N, B), B, 0, stream>>>(ptr, next, bsum, N, E);
  fill_kernel<<<cdiv(E, B), B, 0, stream>>>(src, dst, next, srt, E);

  embed_mm_kernel<T><<<cdiv(N, B), B, 0, stream>>>(x, embed, W1, ptr, bufA, N);
  gather_mm_kernel<T><<<cdiv((long long)N * 16, B), B, 0, stream>>>(
      ptr, srt, bufA, W2, b1, bufB, N);
  gather_fin_kernel<T><<<cdiv((long long)N * 16, B), B, 0, stream>>>(
      ptr, srt, bufB, b2, bufA, N);  // z -> bufA
  predict_kernel<T><<<cdiv(EL, B), B, 0, stream>>>(eli, bufA, fcw, fcb, out, EL);
}

extern "C" void kernel_launch(void* const* d_in, const int* in_sizes, int n_in,
                              void* d_out, int out_size, void* d_ws, size_t ws_size,
                              hipStream_t stream) {
  const int*   x     = (const int*)d_in[0];
  const int*   ei    = (const int*)d_in[1];   // [2,E]
  const int*   eli   = (const int*)d_in[2];   // [2,EL]
  const float* embed = (const float*)d_in[3];
  const float* W1    = (const float*)d_in[4];
  const float* b1    = (const float*)d_in[5];
  const float* W2    = (const float*)d_in[6];
  const float* b2    = (const float*)d_in[7];
  const float* fcw   = (const float*)d_in[8];
  const float* fcb   = (const float*)d_in[9];
  float* out = (float*)d_out;

  const int N  = in_sizes[0];
  const int E  = in_sizes[1] / 2;
  const int EL = in_sizes[2] / 2;
  const int* src = ei;
  const int* dst = ei + E;

  size_t ptrB = ((size_t)(N + 1) * 4 + 255) & ~(size_t)255;
  size_t srtB = ((size_t)E * 4 + 255) & ~(size_t)255;
  size_t bufF = ((size_t)N * 16 * sizeof(float) + 255) & ~(size_t)255;
  size_t bufH = ((size_t)N * 16 * sizeof(bf16) + 255) & ~(size_t)255;

  char* w = (char*)d_ws;
  int* ptr = (int*)w;
  int* srt = (int*)(w + ptrB);
  char* bA = w + ptrB + srtB;

  if (ws_size >= ptrB + srtB + 2 * bufF) {
    run_pipeline<float>(x, src, dst, eli, embed, W1, b1, W2, b2, fcw, fcb, out,
                        N, E, EL, ptr, srt, (float*)bA, (float*)(bA + bufF), stream);
  } else {
    run_pipeline<bf16>(x, src, dst, eli, embed, W1, b1, W2, b2, fcw, fcb, out,
                       N, E, EL, ptr, srt, (bf16*)bA, (bf16*)(bA + bufH), stream);
  }
}

// Round 3
// 818.746 us; speedup vs baseline: 1.4597x; 1.4597x over previous
//
#include <hip/hip_runtime.h>
#include <hip/hip_bf16.h>

// GCN link-prediction, N=1M, D=16, E=5M, EL=2M.
// R3: CSR build via bucketed counting sort (no line-granular random writes):
//   bhist -> bscan -> bin (packed (ldst<<20|src) records into 489 bucket runs)
//   -> csr (per-bucket LDS counting sort; srt writes stay in a 40KB L2 window)
// Gather kernels fuse finalize (+b, relu, *dinv) and the 16x16 GEMM via shfl.

typedef __hip_bfloat16 bf16;

#define BW_SHIFT 11            // bucket node-width = 2048 (needs N <= 1<<20 for packing)
#define BW (1 << BW_SHIFT)
#define NB_MAX 512

template <typename T> struct GIO;

template <> struct GIO<float> {
  static __device__ __forceinline__ float load1(const float* p) { return *p; }
  static __device__ __forceinline__ void store1(float* p, float v) { *p = v; }
  static __device__ __forceinline__ void load16(const float* p, float* h) {
    const float4* q = (const float4*)p;
    float4 a = q[0], b = q[1], c = q[2], d = q[3];
    h[0]=a.x;h[1]=a.y;h[2]=a.z;h[3]=a.w; h[4]=b.x;h[5]=b.y;h[6]=b.z;h[7]=b.w;
    h[8]=c.x;h[9]=c.y;h[10]=c.z;h[11]=c.w; h[12]=d.x;h[13]=d.y;h[14]=d.z;h[15]=d.w;
  }
  static __device__ __forceinline__ void store16(float* p, const float* h) {
    float4* q = (float4*)p;
    q[0]=make_float4(h[0],h[1],h[2],h[3]);
    q[1]=make_float4(h[4],h[5],h[6],h[7]);
    q[2]=make_float4(h[8],h[9],h[10],h[11]);
    q[3]=make_float4(h[12],h[13],h[14],h[15]);
  }
};

template <> struct GIO<bf16> {
  static __device__ __forceinline__ float load1(const bf16* p) { return __bfloat162float(*p); }
  static __device__ __forceinline__ void store1(bf16* p, float v) { *p = __float2bfloat16(v); }
  static __device__ __forceinline__ void load16(const bf16* p, float* h) {
    const uint4* q = (const uint4*)p;
    uint4 a = q[0], b = q[1];
    unsigned u[8] = {a.x,a.y,a.z,a.w,b.x,b.y,b.z,b.w};
#pragma unroll
    for (int j = 0; j < 8; ++j) {
      unsigned short lo = (unsigned short)(u[j] & 0xffffu);
      unsigned short hi = (unsigned short)(u[j] >> 16);
      bf16 bl, bh;
      __builtin_memcpy(&bl, &lo, 2); __builtin_memcpy(&bh, &hi, 2);
      h[2*j]   = __bfloat162float(bl);
      h[2*j+1] = __bfloat162float(bh);
    }
  }
  static __device__ __forceinline__ void store16(bf16* p, const float* h) {
    unsigned short t[16];
#pragma unroll
    for (int j = 0; j < 16; ++j) {
      bf16 b = __float2bfloat16(h[j]);
      __builtin_memcpy(&t[j], &b, 2);
    }
    uint4* q = (uint4*)p;
    uint4 r0, r1;
    __builtin_memcpy(&r0, &t[0], 16);
    __builtin_memcpy(&r1, &t[8], 16);
    q[0] = r0; q[1] = r1;
  }
};

// ---- CSR build ----------------------------------------------------------

// bucket histogram of dst>>BW_SHIFT (8192 edges/block, LDS hist)
__global__ __launch_bounds__(256) void bhist_kernel(
    const int* __restrict__ dst, int* __restrict__ bcnt, int E) {
  __shared__ int h[NB_MAX];
  for (int i = threadIdx.x; i < NB_MAX; i += 256) h[i] = 0;
  __syncthreads();
  int cb = blockIdx.x * 8192;
#pragma unroll 4
  for (int k = 0; k < 32; ++k) {
    int e = cb + k * 256 + threadIdx.x;
    if (e < E) atomicAdd(&h[dst[e] >> BW_SHIFT], 1);
  }
  __syncthreads();
  for (int i = threadIdx.x; i < NB_MAX; i += 256) {
    int c = h[i];
    if (c) atomicAdd(&bcnt[i], c);
  }
}

// one block: exclusive scan of bucket counts -> bbase; init padded cursors
__global__ __launch_bounds__(512) void bscan_kernel(
    const int* __restrict__ bcnt, int* __restrict__ bbase,
    int* __restrict__ bcur, int NB) {
  __shared__ int s[512];
  int t = threadIdx.x;
  int v = (t < NB) ? bcnt[t] : 0;
  s[t] = v;
  __syncthreads();
  for (int off = 1; off < 512; off <<= 1) {
    int x = (t >= off) ? s[t - off] : 0;
    __syncthreads();
    s[t] += x;
    __syncthreads();
  }
  int excl = (t == 0) ? 0 : s[t - 1];
  if (t < NB) { bbase[t] = excl; bcur[t * 16] = excl; }
  if (t == NB - 1) bbase[NB] = excl + v;
}

// bin edges into bucket runs as packed records (ldst<<20 | src).
// One reservation atomic per (block,bucket); per-edge offsets via LDS atomics.
__global__ __launch_bounds__(256) void bin_kernel(
    const int* __restrict__ src, const int* __restrict__ dst,
    int* __restrict__ bcur, unsigned* __restrict__ rec, int E) {
  __shared__ int hist[NB_MAX];
  __shared__ int base[NB_MAX];
  for (int i = threadIdx.x; i < NB_MAX; i += 256) hist[i] = 0;
  __syncthreads();
  int cb = blockIdx.x * 8192;
#pragma unroll 4
  for (int k = 0; k < 32; ++k) {
    int e = cb + k * 256 + threadIdx.x;
    if (e < E) atomicAdd(&hist[dst[e] >> BW_SHIFT], 1);
  }
  __syncthreads();
  for (int i = threadIdx.x; i < NB_MAX; i += 256) {
    int c = hist[i];
    hist[i] = 0;
    base[i] = c ? atomicAdd(&bcur[i * 16], c) : 0;
  }
  __syncthreads();
#pragma unroll 4
  for (int k = 0; k < 32; ++k) {
    int e = cb + k * 256 + threadIdx.x;
    if (e < E) {
      int d = dst[e];
      int b = d >> BW_SHIFT;
      unsigned r = ((unsigned)(d & (BW - 1)) << 20) | (unsigned)src[e];
      int off = atomicAdd(&hist[b], 1);
      rec[base[b] + off] = r;
    }
  }
}

// one block per bucket: LDS counting sort over 2048 local nodes; emit ptr+srt
__global__ __launch_bounds__(256) void csr_kernel(
    const unsigned* __restrict__ rec, const int* __restrict__ bbase,
    int* __restrict__ ptr, int* __restrict__ srt, int N, int NB, int E) {
  __shared__ int cnt[BW];
  __shared__ int s[256];
  int b = blockIdx.x, t = threadIdx.x;
  int rb0 = bbase[b], rb1 = bbase[b + 1];
  for (int i = t; i < BW; i += 256) cnt[i] = 0;
  __syncthreads();
  for (int j = rb0 + t; j < rb1; j += 256) atomicAdd(&cnt[rec[j] >> 20], 1);
  __syncthreads();
  int sum = 0;
#pragma unroll
  for (int j = 0; j < 8; ++j) sum += cnt[t * 8 + j];
  s[t] = sum;
  __syncthreads();
  for (int off = 1; off < 256; off <<= 1) {
    int x = (t >= off) ? s[t - off] : 0;
    __syncthreads();
    s[t] += x;
    __syncthreads();
  }
  int run = (t == 0) ? 0 : s[t - 1];
  int nb0 = b << BW_SHIFT;
#pragma unroll
  for (int j = 0; j < 8; ++j) {
    int idx = t * 8 + j;
    int c = cnt[idx];
    cnt[idx] = run;                       // becomes local cursor
    int node = nb0 + idx;
    if (node < N) ptr[node] = rb0 + run;
    run += c;
  }
  __syncthreads();
  for (int j = rb0 + t; j < rb1; j += 256) {
    unsigned r = rec[j];
    int off = atomicAdd(&cnt[r >> 20], 1);
    srt[rb0 + off] = (int)(r & 0xFFFFFu);  // writes stay in bucket's ~40KB window
  }
  if (b == NB - 1 && t == 0) ptr[N] = E;
}

// ---- dense per-node kernels --------------------------------------------

// g[i,:] = (embed[x[i],:] @ W1) * dinv[i]
template <typename T>
__global__ __launch_bounds__(256) void embed_mm_kernel(
    const int* __restrict__ x, const float* __restrict__ embed,
    const float* __restrict__ W, const int* __restrict__ ptr,
    T* __restrict__ g, int n) {
  __shared__ float Ws[256];
  Ws[threadIdx.x] = W[threadIdx.x];
  __syncthreads();
  int i = blockIdx.x * 256 + threadIdx.x;
  if (i >= n) return;
  float dv = rsqrtf((float)(ptr[i + 1] - ptr[i]) + 1.0f);
  int row = x[i];
  float h[16];
  GIO<float>::load16(embed + (size_t)row * 16, h);
  float o[16];
#pragma unroll
  for (int j = 0; j < 16; ++j) o[j] = 0.f;
#pragma unroll
  for (int k = 0; k < 16; ++k) {
    float hk = h[k];
#pragma unroll
    for (int j = 0; j < 16; ++j) o[j] = fmaf(hk, Ws[k * 16 + j], o[j]);
  }
#pragma unroll
  for (int j = 0; j < 16; ++j) o[j] *= dv;
  GIO<T>::store16(g + (size_t)i * 16, o);
}

// 16 lanes per node: acc = g1[d] + sum g1[srt[j]]; h = relu(dv*acc + b1);
// g2[d] = (h @ W2) * dv   (GEMM across the 16-lane group via shfl)
template <typename T>
__global__ __launch_bounds__(256) void gather_mm_kernel(
    const int* __restrict__ ptr, const int* __restrict__ srt,
    const T* __restrict__ g1, const float* __restrict__ W,
    const float* __restrict__ bias, T* __restrict__ g2, int n) {
  __shared__ float Ws[256];
  __shared__ float bs[16];
  Ws[threadIdx.x] = W[threadIdx.x];
  if (threadIdx.x < 16) bs[threadIdx.x] = bias[threadIdx.x];
  __syncthreads();
  int t = blockIdx.x * 256 + threadIdx.x;
  int d = t >> 4;
  if (d >= n) return;
  int f = t & 15;
  int p0 = ptr[d], p1 = ptr[d + 1];
  float dv = rsqrtf((float)(p1 - p0) + 1.0f);
  float acc = GIO<T>::load1(g1 + (size_t)d * 16 + f);
  for (int j = p0; j < p1; ++j) {
    int s = srt[j];
    acc += GIO<T>::load1(g1 + (size_t)s * 16 + f);
  }
  float h = fmaxf(fmaf(dv, acc, bs[f]), 0.f);
  float o = 0.f;
#pragma unroll
  for (int k = 0; k < 16; ++k) o = fmaf(__shfl(h, k, 16), Ws[k * 16 + f], o);
  GIO<T>::store1(g2 + (size_t)d * 16 + f, o * dv);
}

// z[d] = dv * (g2[d] + sum g2[srt[j]]) + b2
template <typename T>
__global__ __launch_bounds__(256) void gather_fin_kernel(
    const int* __restrict__ ptr, const int* __restrict__ srt,
    const T* __restrict__ g2, const float* __restrict__ bias,
    T* __restrict__ z, int n) {
  __shared__ float bs[16];
  if (threadIdx.x < 16) bs[threadIdx.x] = bias[threadIdx.x];
  __syncthreads();
  int t = blockIdx.x * 256 + threadIdx.x;
  int d = t >> 4;
  if (d >= n) return;
  int f = t & 15;
  int p0 = ptr[d], p1 = ptr[d + 1];
  float dv = rsqrtf((float)(p1 - p0) + 1.0f);
  float acc = GIO<T>::load1(g2 + (size_t)d * 16 + f);
  for (int j = p0; j < p1; ++j) {
    int s = srt[j];
    acc += GIO<T>::load1(g2 + (size_t)s * 16 + f);
  }
  GIO<T>::store1(z + (size_t)d * 16 + f, fmaf(dv, acc, bs[f]));
}

// out[e] = [z[a], z[b]] . fc_w + fc_b
template <typename T>
__global__ __launch_bounds__(256) void predict_kernel(
    const int* __restrict__ eli, const T* __restrict__ z,
    const float* __restrict__ fcw, const float* __restrict__ fcb,
    float* __restrict__ out, int EL) {
  __shared__ float w[32];
  __shared__ float bb;
  if (threadIdx.x < 32) w[threadIdx.x] = fcw[threadIdx.x];
  if (threadIdx.x == 0) bb = fcb[0];
  __syncthreads();
  int e = blockIdx.x * 256 + threadIdx.x;
  if (e >= EL) return;
  int a = eli[e], b = eli[EL + e];
  float za[16], zb[16];
  GIO<T>::load16(z + (size_t)a * 16, za);
  GIO<T>::load16(z + (size_t)b * 16, zb);
  float s = bb;
#pragma unroll
  for (int j = 0; j < 16; ++j) s = fmaf(za[j], w[j], s);
#pragma unroll
  for (int j = 0; j < 16; ++j) s = fmaf(zb[j], w[16 + j], s);
  out[e] = s;
}

static inline int cdiv(long long a, long long b) { return (int)((a + b - 1) / b); }

template <typename T>
static void run_pipeline(const int* x, const int* src, const int* dst,
                         const int* eli, const float* embed,
                         const float* W1, const float* b1,
                         const float* W2, const float* b2,
                         const float* fcw, const float* fcb, float* out,
                         int N, int E, int EL,
                         int* ptr, int* srt, T* bufA, T* bufB,
                         hipStream_t stream) {
  // small CSR-build arrays aliased into bufA (dead until embed_mm writes it);
  // packed edge records aliased into bufB (dead until gather_mm writes it)
  char* bA = (char*)bufA;
  int* bcnt  = (int*)bA;                 // [NB_MAX]
  int* bbase = (int*)(bA + 4096);        // [NB+1]
  int* bcur  = (int*)(bA + 8192);        // [NB_MAX*16] padded cursors (64B apart)
  unsigned* rec = (unsigned*)bufB;       // [E]

  const int B = 256;
  const int NB = cdiv(N, BW);

  hipMemsetAsync(bcnt, 0, NB_MAX * 4, stream);
  bhist_kernel<<<cdiv(E, 8192), B, 0, stream>>>(dst, bcnt, E);
  bscan_kernel<<<1, 512, 0, stream>>>(bcnt, bbase, bcur, NB);
  bin_kernel<<<cdiv(E, 8192), B, 0, stream>>>(src, dst, bcur, rec, E);
  csr_kernel<<<NB, B, 0, stream>>>(rec, bbase, ptr, srt, N, NB, E);

  embed_mm_kernel<T><<<cdiv(N, B), B, 0, stream>>>(x, embed, W1, ptr, bufA, N);
  gather_mm_kernel<T><<<cdiv((long long)N * 16, B), B, 0, stream>>>(
      ptr, srt, bufA, W2, b1, bufB, N);
  gather_fin_kernel<T><<<cdiv((long long)N * 16, B), B, 0, stream>>>(
      ptr, srt, bufB, b2, bufA, N);  // z -> bufA
  predict_kernel<T><<<cdiv(EL, B), B, 0, stream>>>(eli, bufA, fcw, fcb, out, EL);
}

extern "C" void kernel_launch(void* const* d_in, const int* in_sizes, int n_in,
                              void* d_out, int out_size, void* d_ws, size_t ws_size,
                              hipStream_t stream) {
  const int*   x     = (const int*)d_in[0];
  const int*   ei    = (const int*)d_in[1];   // [2,E]
  const int*   eli   = (const int*)d_in[2];   // [2,EL]
  const float* embed = (const float*)d_in[3];
  const float* W1    = (const float*)d_in[4];
  const float* b1    = (const float*)d_in[5];
  const float* W2    = (const float*)d_in[6];
  const float* b2    = (const float*)d_in[7];
  const float* fcw   = (const float*)d_in[8];
  const float* fcb   = (const float*)d_in[9];
  float* out = (float*)d_out;

  const int N  = in_sizes[0];
  const int E  = in_sizes[1] / 2;
  const int EL = in_sizes[2] / 2;
  const int* src = ei;
  const int* dst = ei + E;

  size_t ptrB = ((size_t)(N + 1) * 4 + 255) & ~(size_t)255;
  size_t srtB = ((size_t)E * 4 + 255) & ~(size_t)255;
  size_t bufF = ((size_t)N * 16 * sizeof(float) + 255) & ~(size_t)255;
  size_t bufH = ((size_t)N * 16 * sizeof(bf16) + 255) & ~(size_t)255;

  char* w = (char*)d_ws;
  int* ptr = (int*)w;
  int* srt = (int*)(w + ptrB);
  char* bA = w + ptrB + srtB;

  if (ws_size >= ptrB + srtB + 2 * bufF) {
    run_pipeline<float>(x, src, dst, eli, embed, W1, b1, W2, b2, fcw, fcb, out,
                        N, E, EL, ptr, srt, (float*)bA, (float*)(bA + bufF), stream);
  } else {
    run_pipeline<bf16>(x, src, dst, eli, embed, W1, b1, W2, b2, fcw, fcb, out,
                       N, E, EL, ptr, srt, (bf16*)bA, (bf16*)(bA + bufH), stream);
  }
}

// Round 4
// 585.779 us; speedup vs baseline: 2.0403x; 1.3977x over previous
//
#include <hip/hip_runtime.h>
#include <hip/hip_bf16.h>

// GCN link-prediction, N=1M, D=16, E=5M, EL=2M.
// R4: gather kernels redesigned to 4 lanes/node with vector row loads and
// 4-way unrolled independent load chains (probe: latency- vs fill-rate-bound).
// Layer-2 gather folds the fc head: emits u[i]=z[i].w_hi, v[i]=z[i].w_lo
// (8 MB hot) so predict does 4B gathers instead of 64B row fills.
// CSR build (bucketed counting sort) unchanged from R3.

typedef __hip_bfloat16 bf16;

#define BW_SHIFT 11            // bucket node-width = 2048 (needs N <= 1<<20 for packing)
#define BW (1 << BW_SHIFT)
#define NB_MAX 512

__device__ __forceinline__ float bf2f(unsigned short s) {
  unsigned u = ((unsigned)s) << 16; float f; __builtin_memcpy(&f, &u, 4); return f;
}
__device__ __forceinline__ unsigned short f2bf(float f) {
  bf16 b = __float2bfloat16(f); unsigned short s; __builtin_memcpy(&s, &b, 2); return s;
}
__device__ __forceinline__ float4 add4(float4 a, float4 b) {
  return make_float4(a.x + b.x, a.y + b.y, a.z + b.z, a.w + b.w);
}

template <typename T> struct GIO;

template <> struct GIO<float> {
  // 4 consecutive feats (16B)
  static __device__ __forceinline__ float4 loadv(const float* p) { return *(const float4*)p; }
  static __device__ __forceinline__ void storev(float* p, float4 v) { *(float4*)p = v; }
  static __device__ __forceinline__ void load16(const float* p, float* h) {
    const float4* q = (const float4*)p;
    float4 a = q[0], b = q[1], c = q[2], d = q[3];
    h[0]=a.x;h[1]=a.y;h[2]=a.z;h[3]=a.w; h[4]=b.x;h[5]=b.y;h[6]=b.z;h[7]=b.w;
    h[8]=c.x;h[9]=c.y;h[10]=c.z;h[11]=c.w; h[12]=d.x;h[13]=d.y;h[14]=d.z;h[15]=d.w;
  }
  static __device__ __forceinline__ void store16(float* p, const float* h) {
    float4* q = (float4*)p;
    q[0]=make_float4(h[0],h[1],h[2],h[3]);
    q[1]=make_float4(h[4],h[5],h[6],h[7]);
    q[2]=make_float4(h[8],h[9],h[10],h[11]);
    q[3]=make_float4(h[12],h[13],h[14],h[15]);
  }
};

template <> struct GIO<bf16> {
  static __device__ __forceinline__ float4 loadv(const bf16* p) {
    ushort4 u = *(const ushort4*)p;  // 8B
    return make_float4(bf2f(u.x), bf2f(u.y), bf2f(u.z), bf2f(u.w));
  }
  static __device__ __forceinline__ void storev(bf16* p, float4 v) {
    ushort4 u = make_ushort4(f2bf(v.x), f2bf(v.y), f2bf(v.z), f2bf(v.w));
    *(ushort4*)p = u;
  }
  static __device__ __forceinline__ void store16(bf16* p, const float* h) {
    unsigned short t[16];
#pragma unroll
    for (int j = 0; j < 16; ++j) t[j] = f2bf(h[j]);
    uint4 r0, r1;
    __builtin_memcpy(&r0, &t[0], 16);
    __builtin_memcpy(&r1, &t[8], 16);
    uint4* q = (uint4*)p;
    q[0] = r0; q[1] = r1;
  }
};

// ---- CSR build ----------------------------------------------------------

__global__ __launch_bounds__(256) void bhist_kernel(
    const int* __restrict__ dst, int* __restrict__ bcnt, int E) {
  __shared__ int h[NB_MAX];
  for (int i = threadIdx.x; i < NB_MAX; i += 256) h[i] = 0;
  __syncthreads();
  int cb = blockIdx.x * 8192;
#pragma unroll 4
  for (int k = 0; k < 32; ++k) {
    int e = cb + k * 256 + threadIdx.x;
    if (e < E) atomicAdd(&h[dst[e] >> BW_SHIFT], 1);
  }
  __syncthreads();
  for (int i = threadIdx.x; i < NB_MAX; i += 256) {
    int c = h[i];
    if (c) atomicAdd(&bcnt[i], c);
  }
}

__global__ __launch_bounds__(512) void bscan_kernel(
    const int* __restrict__ bcnt, int* __restrict__ bbase,
    int* __restrict__ bcur, int NB) {
  __shared__ int s[512];
  int t = threadIdx.x;
  int v = (t < NB) ? bcnt[t] : 0;
  s[t] = v;
  __syncthreads();
  for (int off = 1; off < 512; off <<= 1) {
    int x = (t >= off) ? s[t - off] : 0;
    __syncthreads();
    s[t] += x;
    __syncthreads();
  }
  int excl = (t == 0) ? 0 : s[t - 1];
  if (t < NB) { bbase[t] = excl; bcur[t * 16] = excl; }
  if (t == NB - 1) bbase[NB] = excl + v;
}

__global__ __launch_bounds__(256) void bin_kernel(
    const int* __restrict__ src, const int* __restrict__ dst,
    int* __restrict__ bcur, unsigned* __restrict__ rec, int E) {
  __shared__ int hist[NB_MAX];
  __shared__ int base[NB_MAX];
  for (int i = threadIdx.x; i < NB_MAX; i += 256) hist[i] = 0;
  __syncthreads();
  int cb = blockIdx.x * 8192;
#pragma unroll 4
  for (int k = 0; k < 32; ++k) {
    int e = cb + k * 256 + threadIdx.x;
    if (e < E) atomicAdd(&hist[dst[e] >> BW_SHIFT], 1);
  }
  __syncthreads();
  for (int i = threadIdx.x; i < NB_MAX; i += 256) {
    int c = hist[i];
    hist[i] = 0;
    base[i] = c ? atomicAdd(&bcur[i * 16], c) : 0;
  }
  __syncthreads();
#pragma unroll 4
  for (int k = 0; k < 32; ++k) {
    int e = cb + k * 256 + threadIdx.x;
    if (e < E) {
      int d = dst[e];
      int b = d >> BW_SHIFT;
      unsigned r = ((unsigned)(d & (BW - 1)) << 20) | (unsigned)src[e];
      int off = atomicAdd(&hist[b], 1);
      rec[base[b] + off] = r;
    }
  }
}

__global__ __launch_bounds__(256) void csr_kernel(
    const unsigned* __restrict__ rec, const int* __restrict__ bbase,
    int* __restrict__ ptr, int* __restrict__ srt, int N, int NB, int E) {
  __shared__ int cnt[BW];
  __shared__ int s[256];
  int b = blockIdx.x, t = threadIdx.x;
  int rb0 = bbase[b], rb1 = bbase[b + 1];
  for (int i = t; i < BW; i += 256) cnt[i] = 0;
  __syncthreads();
  for (int j = rb0 + t; j < rb1; j += 256) atomicAdd(&cnt[rec[j] >> 20], 1);
  __syncthreads();
  int sum = 0;
#pragma unroll
  for (int j = 0; j < 8; ++j) sum += cnt[t * 8 + j];
  s[t] = sum;
  __syncthreads();
  for (int off = 1; off < 256; off <<= 1) {
    int x = (t >= off) ? s[t - off] : 0;
    __syncthreads();
    s[t] += x;
    __syncthreads();
  }
  int run = (t == 0) ? 0 : s[t - 1];
  int nb0 = b << BW_SHIFT;
#pragma unroll
  for (int j = 0; j < 8; ++j) {
    int idx = t * 8 + j;
    int c = cnt[idx];
    cnt[idx] = run;                       // becomes local cursor
    int node = nb0 + idx;
    if (node < N) ptr[node] = rb0 + run;
    run += c;
  }
  __syncthreads();
  for (int j = rb0 + t; j < rb1; j += 256) {
    unsigned r = rec[j];
    int off = atomicAdd(&cnt[r >> 20], 1);
    srt[rb0 + off] = (int)(r & 0xFFFFFu);
  }
  if (b == NB - 1 && t == 0) ptr[N] = E;
}

// ---- dense per-node kernels --------------------------------------------

// g[i,:] = (embed[x[i],:] @ W1) * dinv[i]   (x is iota -> streaming)
template <typename T>
__global__ __launch_bounds__(256) void embed_mm_kernel(
    const int* __restrict__ x, const float* __restrict__ embed,
    const float* __restrict__ W, const int* __restrict__ ptr,
    T* __restrict__ g, int n) {
  __shared__ float Ws[256];
  Ws[threadIdx.x] = W[threadIdx.x];
  __syncthreads();
  int i = blockIdx.x * 256 + threadIdx.x;
  if (i >= n) return;
  float dv = rsqrtf((float)(ptr[i + 1] - ptr[i]) + 1.0f);
  int row = x[i];
  float h[16];
  GIO<float>::load16(embed + (size_t)row * 16, h);
  float o[16];
#pragma unroll
  for (int j = 0; j < 16; ++j) o[j] = 0.f;
#pragma unroll
  for (int k = 0; k < 16; ++k) {
    float hk = h[k];
#pragma unroll
    for (int j = 0; j < 16; ++j) o[j] = fmaf(hk, Ws[k * 16 + j], o[j]);
  }
#pragma unroll
  for (int j = 0; j < 16; ++j) o[j] *= dv;
  GIO<T>::store16(g + (size_t)i * 16, o);
}

// shared neighbor-accumulate: 4 lanes/node, lane q owns feats [4q,4q+4).
// 4-way unrolled, two independent chains -> up to ~5 outstanding fills/lane.
template <typename T>
__device__ __forceinline__ float4 gather_acc(
    const int* __restrict__ srt, const T* __restrict__ g,
    int d, int q, int p0, int p1) {
  const T* gq = g + q * 4;
  float4 acc0 = GIO<T>::loadv(g + (size_t)d * 16 + q * 4);  // self row
  float4 acc1 = make_float4(0.f, 0.f, 0.f, 0.f);
  int j = p0;
  for (; j + 4 <= p1; j += 4) {
    int s0 = srt[j], s1 = srt[j + 1], s2 = srt[j + 2], s3 = srt[j + 3];
    float4 r0 = GIO<T>::loadv(gq + (size_t)s0 * 16);
    float4 r1 = GIO<T>::loadv(gq + (size_t)s1 * 16);
    float4 r2 = GIO<T>::loadv(gq + (size_t)s2 * 16);
    float4 r3 = GIO<T>::loadv(gq + (size_t)s3 * 16);
    acc0 = add4(acc0, add4(r0, r2));
    acc1 = add4(acc1, add4(r1, r3));
  }
  for (; j < p1; ++j)
    acc1 = add4(acc1, GIO<T>::loadv(gq + (size_t)srt[j] * 16));
  return add4(acc0, acc1);
}

// layer-1 gather + finalize + 16x16 GEMM (h broadcast via 4-lane shfl)
template <typename T>
__global__ __launch_bounds__(256) void gather_mm_kernel(
    const int* __restrict__ ptr, const int* __restrict__ srt,
    const T* __restrict__ g1, const float* __restrict__ W,
    const float* __restrict__ bias, T* __restrict__ g2, int n) {
  __shared__ float Ws[256];
  __shared__ float bs[16];
  Ws[threadIdx.x] = W[threadIdx.x];
  if (threadIdx.x < 16) bs[threadIdx.x] = bias[threadIdx.x];
  __syncthreads();
  int t = blockIdx.x * 256 + threadIdx.x;
  int d = t >> 2;
  if (d >= n) return;
  int q = t & 3;
  int p0 = ptr[d], p1 = ptr[d + 1];
  float dv = rsqrtf((float)(p1 - p0) + 1.0f);
  float4 acc = gather_acc<T>(srt, g1, d, q, p0, p1);
  float4 b4 = *(const float4*)&bs[q * 4];
  float4 h = make_float4(fmaxf(fmaf(dv, acc.x, b4.x), 0.f),
                         fmaxf(fmaf(dv, acc.y, b4.y), 0.f),
                         fmaxf(fmaf(dv, acc.z, b4.z), 0.f),
                         fmaxf(fmaf(dv, acc.w, b4.w), 0.f));
  float4 o = make_float4(0.f, 0.f, 0.f, 0.f);
#pragma unroll
  for (int m = 0; m < 4; ++m) {
    float4 hm = make_float4(__shfl(h.x, m, 4), __shfl(h.y, m, 4),
                            __shfl(h.z, m, 4), __shfl(h.w, m, 4));
    const float* wr = &Ws[(4 * m) * 16 + q * 4];
    float4 w0 = *(const float4*)(wr);
    float4 w1 = *(const float4*)(wr + 16);
    float4 w2 = *(const float4*)(wr + 32);
    float4 w3 = *(const float4*)(wr + 48);
    o.x = fmaf(hm.x, w0.x, fmaf(hm.y, w1.x, fmaf(hm.z, w2.x, fmaf(hm.w, w3.x, o.x))));
    o.y = fmaf(hm.x, w0.y, fmaf(hm.y, w1.y, fmaf(hm.z, w2.y, fmaf(hm.w, w3.y, o.y))));
    o.z = fmaf(hm.x, w0.z, fmaf(hm.y, w1.z, fmaf(hm.z, w2.z, fmaf(hm.w, w3.z, o.z))));
    o.w = fmaf(hm.x, w0.w, fmaf(hm.y, w1.w, fmaf(hm.z, w2.w, fmaf(hm.w, w3.w, o.w))));
  }
  o = make_float4(o.x * dv, o.y * dv, o.z * dv, o.w * dv);
  GIO<T>::storev(g2 + (size_t)d * 16 + q * 4, o);
}

// layer-2 gather + finalize + fc fold: u[d] = z.w[0:16], v[d] = z.w[16:32]
template <typename T>
__global__ __launch_bounds__(256) void gather_fin_uv_kernel(
    const int* __restrict__ ptr, const int* __restrict__ srt,
    const T* __restrict__ g2, const float* __restrict__ bias,
    const float* __restrict__ fcw, float* __restrict__ u,
    float* __restrict__ v, int n) {
  __shared__ float bs[16];
  __shared__ float wv[32];
  if (threadIdx.x < 16) bs[threadIdx.x] = bias[threadIdx.x];
  if (threadIdx.x < 32) wv[threadIdx.x] = fcw[threadIdx.x];
  __syncthreads();
  int t = blockIdx.x * 256 + threadIdx.x;
  int d = t >> 2;
  if (d >= n) return;
  int q = t & 3;
  int p0 = ptr[d], p1 = ptr[d + 1];
  float dv = rsqrtf((float)(p1 - p0) + 1.0f);
  float4 acc = gather_acc<T>(srt, g2, d, q, p0, p1);
  float4 b4 = *(const float4*)&bs[q * 4];
  float4 z = make_float4(fmaf(dv, acc.x, b4.x), fmaf(dv, acc.y, b4.y),
                         fmaf(dv, acc.z, b4.z), fmaf(dv, acc.w, b4.w));
  float4 wu = *(const float4*)&wv[q * 4];
  float4 wl = *(const float4*)&wv[16 + q * 4];
  float pu = fmaf(z.x, wu.x, fmaf(z.y, wu.y, fmaf(z.z, wu.z, z.w * wu.w)));
  float pv = fmaf(z.x, wl.x, fmaf(z.y, wl.y, fmaf(z.z, wl.z, z.w * wl.w)));
  pu += __shfl_xor(pu, 1, 4); pu += __shfl_xor(pu, 2, 4);
  pv += __shfl_xor(pv, 1, 4); pv += __shfl_xor(pv, 2, 4);
  if (q == 0) u[d] = pu;
  if (q == 1) v[d] = pv;
}

// out[e] = u[a] + v[b] + fc_b   (4B gathers from 8MB hot arrays)
__global__ __launch_bounds__(256) void predict_kernel(
    const int* __restrict__ eli, const float* __restrict__ u,
    const float* __restrict__ v, const float* __restrict__ fcb,
    float* __restrict__ out, int EL) {
  int e = blockIdx.x * 256 + threadIdx.x;
  if (e >= EL) return;
  int a = eli[e], b = eli[EL + e];
  out[e] = u[a] + v[b] + fcb[0];
}

static inline int cdiv(long long a, long long b) { return (int)((a + b - 1) / b); }

template <typename T>
static void run_pipeline(const int* x, const int* src, const int* dst,
                         const int* eli, const float* embed,
                         const float* W1, const float* b1,
                         const float* W2, const float* b2,
                         const float* fcw, const float* fcb, float* out,
                         int N, int E, int EL,
                         int* ptr, int* srt, T* bufA, T* bufB,
                         hipStream_t stream) {
  // CSR-build scratch aliased into bufA (dead until embed_mm writes it);
  // packed edge records aliased into bufB (dead until gather_mm writes it);
  // u/v aliased into bufA (g1 dead once gather_fin_uv runs).
  char* bA = (char*)bufA;
  int* bcnt  = (int*)bA;                 // [NB_MAX]
  int* bbase = (int*)(bA + 4096);        // [NB+1]
  int* bcur  = (int*)(bA + 8192);        // [NB_MAX*16] padded cursors
  unsigned* rec = (unsigned*)bufB;       // [E]
  float* u = (float*)bA;                 // [N]
  float* v = u + N;                      // [N]

  const int B = 256;
  const int NB = cdiv(N, BW);

  hipMemsetAsync(bcnt, 0, NB_MAX * 4, stream);
  bhist_kernel<<<cdiv(E, 8192), B, 0, stream>>>(dst, bcnt, E);
  bscan_kernel<<<1, 512, 0, stream>>>(bcnt, bbase, bcur, NB);
  bin_kernel<<<cdiv(E, 8192), B, 0, stream>>>(src, dst, bcur, rec, E);
  csr_kernel<<<NB, B, 0, stream>>>(rec, bbase, ptr, srt, N, NB, E);

  embed_mm_kernel<T><<<cdiv(N, B), B, 0, stream>>>(x, embed, W1, ptr, bufA, N);
  gather_mm_kernel<T><<<cdiv((long long)N * 4, B), B, 0, stream>>>(
      ptr, srt, bufA, W2, b1, bufB, N);
  gather_fin_uv_kernel<T><<<cdiv((long long)N * 4, B), B, 0, stream>>>(
      ptr, srt, bufB, b2, fcw, u, v, N);
  predict_kernel<<<cdiv(EL, B), B, 0, stream>>>(eli, u, v, fcb, out, EL);
}

extern "C" void kernel_launch(void* const* d_in, const int* in_sizes, int n_in,
                              void* d_out, int out_size, void* d_ws, size_t ws_size,
                              hipStream_t stream) {
  const int*   x     = (const int*)d_in[0];
  const int*   ei    = (const int*)d_in[1];   // [2,E]
  const int*   eli   = (const int*)d_in[2];   // [2,EL]
  const float* embed = (const float*)d_in[3];
  const float* W1    = (const float*)d_in[4];
  const float* b1    = (const float*)d_in[5];
  const float* W2    = (const float*)d_in[6];
  const float* b2    = (const float*)d_in[7];
  const float* fcw   = (const float*)d_in[8];
  const float* fcb   = (const float*)d_in[9];
  float* out = (float*)d_out;

  const int N  = in_sizes[0];
  const int E  = in_sizes[1] / 2;
  const int EL = in_sizes[2] / 2;
  const int* src = ei;
  const int* dst = ei + E;

  size_t ptrB = ((size_t)(N + 1) * 4 + 255) & ~(size_t)255;
  size_t srtB = ((size_t)E * 4 + 255) & ~(size_t)255;
  size_t bufF = ((size_t)N * 16 * sizeof(float) + 255) & ~(size_t)255;
  size_t bufH = ((size_t)N * 16 * sizeof(bf16) + 255) & ~(size_t)255;

  char* w = (char*)d_ws;
  int* ptr = (int*)w;
  int* srt = (int*)(w + ptrB);
  char* bA = w + ptrB + srtB;

  if (ws_size >= ptrB + srtB + 2 * bufF) {
    run_pipeline<float>(x, src, dst, eli, embed, W1, b1, W2, b2, fcw, fcb, out,
                        N, E, EL, ptr, srt, (float*)bA, (float*)(bA + bufF), stream);
  } else {
    run_pipeline<bf16>(x, src, dst, eli, embed, W1, b1, W2, b2, fcw, fcb, out,
                       N, E, EL, ptr, srt, (bf16*)bA, (bf16*)(bA + bufH), stream);
  }
}

// Round 5
// 508.719 us; speedup vs baseline: 2.3493x; 1.1515x over previous
//
#include <hip/hip_runtime.h>
#include <hip/hip_bf16.h>

// GCN link-prediction, N=1M, D=16, E=5M, EL=2M.
// R5: (1) bin_kernel stages records in LDS sorted by bucket, then writes
// linearly (coalesced, ~1 line-touch per record) -> kills 6x write amp.
// (2) fc head folded through layer-2 aggregation: gather_mm emits per-node
// scalars qu=dv*h.(W2 w_hi), qv=dv*h.(W2 w_lo); layer-2 gather is float2
// gathers from an 8MB L2-resident table; g2 never materialized.
// CSR build otherwise as R3; gathers 4-lane/node unrolled as R4.

typedef __hip_bfloat16 bf16;

#define BW_SHIFT 11            // bucket node-width = 2048 (needs N <= 1<<20)
#define BW (1 << BW_SHIFT)
#define NB_MAX 512
#define CHUNK 16384            // edges per bin block (64KB LDS stage)

__device__ __forceinline__ float bf2f(unsigned short s) {
  unsigned u = ((unsigned)s) << 16; float f; __builtin_memcpy(&f, &u, 4); return f;
}
__device__ __forceinline__ unsigned short f2bf(float f) {
  bf16 b = __float2bfloat16(f); unsigned short s; __builtin_memcpy(&s, &b, 2); return s;
}
__device__ __forceinline__ float4 add4(float4 a, float4 b) {
  return make_float4(a.x + b.x, a.y + b.y, a.z + b.z, a.w + b.w);
}

template <typename T> struct GIO;

template <> struct GIO<float> {
  static __device__ __forceinline__ float4 loadv(const float* p) { return *(const float4*)p; }
  static __device__ __forceinline__ void load16(const float* p, float* h) {
    const float4* q = (const float4*)p;
    float4 a = q[0], b = q[1], c = q[2], d = q[3];
    h[0]=a.x;h[1]=a.y;h[2]=a.z;h[3]=a.w; h[4]=b.x;h[5]=b.y;h[6]=b.z;h[7]=b.w;
    h[8]=c.x;h[9]=c.y;h[10]=c.z;h[11]=c.w; h[12]=d.x;h[13]=d.y;h[14]=d.z;h[15]=d.w;
  }
  static __device__ __forceinline__ void store16(float* p, const float* h) {
    float4* q = (float4*)p;
    q[0]=make_float4(h[0],h[1],h[2],h[3]);
    q[1]=make_float4(h[4],h[5],h[6],h[7]);
    q[2]=make_float4(h[8],h[9],h[10],h[11]);
    q[3]=make_float4(h[12],h[13],h[14],h[15]);
  }
};

template <> struct GIO<bf16> {
  static __device__ __forceinline__ float4 loadv(const bf16* p) {
    ushort4 u = *(const ushort4*)p;  // 8B
    return make_float4(bf2f(u.x), bf2f(u.y), bf2f(u.z), bf2f(u.w));
  }
  static __device__ __forceinline__ void store16(bf16* p, const float* h) {
    unsigned short t[16];
#pragma unroll
    for (int j = 0; j < 16; ++j) t[j] = f2bf(h[j]);
    uint4 r0, r1;
    __builtin_memcpy(&r0, &t[0], 16);
    __builtin_memcpy(&r1, &t[8], 16);
    uint4* q = (uint4*)p;
    q[0] = r0; q[1] = r1;
  }
};

// ---- CSR build ----------------------------------------------------------

__global__ __launch_bounds__(256) void bhist_kernel(
    const int* __restrict__ dst, int* __restrict__ bcnt, int E) {
  __shared__ int h[NB_MAX];
  for (int i = threadIdx.x; i < NB_MAX; i += 256) h[i] = 0;
  __syncthreads();
  int cb = blockIdx.x * 8192;
#pragma unroll 4
  for (int k = 0; k < 32; ++k) {
    int e = cb + k * 256 + threadIdx.x;
    if (e < E) atomicAdd(&h[dst[e] >> BW_SHIFT], 1);
  }
  __syncthreads();
  for (int i = threadIdx.x; i < NB_MAX; i += 256) {
    int c = h[i];
    if (c) atomicAdd(&bcnt[i], c);
  }
}

__global__ __launch_bounds__(512) void bscan_kernel(
    const int* __restrict__ bcnt, int* __restrict__ bbase,
    int* __restrict__ bcur, int NB) {
  __shared__ int s[512];
  int t = threadIdx.x;
  int v = (t < NB) ? bcnt[t] : 0;
  s[t] = v;
  __syncthreads();
  for (int off = 1; off < 512; off <<= 1) {
    int x = (t >= off) ? s[t - off] : 0;
    __syncthreads();
    s[t] += x;
    __syncthreads();
  }
  int excl = (t == 0) ? 0 : s[t - 1];
  if (t < NB) { bbase[t] = excl; bcur[t * 16] = excl; }
  if (t == NB - 1) bbase[NB] = excl + v;
}

// bin edges into bucket runs as packed records (ldst<<20 | src), LDS-staged:
// per-chunk hist -> scan -> LDS scatter (bucket-sorted) -> linear coalesced
// global write via binary-searched bucket delta.
__global__ __launch_bounds__(256) void bin_kernel(
    const int* __restrict__ src, const int* __restrict__ dst,
    int* __restrict__ bcur, unsigned* __restrict__ rec, int E) {
  __shared__ int hist[NB_MAX];
  __shared__ int excl[NB_MAX];
  __shared__ int gdel[NB_MAX];
  __shared__ int cur[NB_MAX];
  __shared__ int s[256];
  __shared__ unsigned stage[CHUNK];
  int t = threadIdx.x;
  hist[t] = 0; hist[t + 256] = 0;
  __syncthreads();
  int cb = blockIdx.x * CHUNK;
  int cend = E - cb; if (cend > CHUNK) cend = CHUNK;
  // pass 1: count
#pragma unroll 4
  for (int k = 0; k < CHUNK / 256; ++k) {
    int i = k * 256 + t;
    if (i < cend) atomicAdd(&hist[dst[cb + i] >> BW_SHIFT], 1);
  }
  __syncthreads();
  // scan 512 entries with 256 threads
  int a0 = hist[2 * t], a1 = hist[2 * t + 1];
  s[t] = a0 + a1;
  __syncthreads();
  for (int off = 1; off < 256; off <<= 1) {
    int x = (t >= off) ? s[t - off] : 0;
    __syncthreads();
    s[t] += x;
    __syncthreads();
  }
  int e0 = (t == 0) ? 0 : s[t - 1];
  excl[2 * t] = e0; excl[2 * t + 1] = e0 + a0;
  cur[2 * t] = e0;  cur[2 * t + 1] = e0 + a0;
  if (a0) gdel[2 * t]     = atomicAdd(&bcur[(2 * t) * 16], a0)     - e0;
  if (a1) gdel[2 * t + 1] = atomicAdd(&bcur[(2 * t + 1) * 16], a1) - (e0 + a0);
  __syncthreads();
  // pass 2: scatter records into LDS, bucket-sorted
#pragma unroll 4
  for (int k = 0; k < CHUNK / 256; ++k) {
    int i = k * 256 + t;
    if (i < cend) {
      int d = dst[cb + i];
      int b = d >> BW_SHIFT;
      unsigned r = ((unsigned)(d & (BW - 1)) << 20) | (unsigned)src[cb + i];
      int off = atomicAdd(&cur[b], 1);
      stage[off] = r;
    }
  }
  __syncthreads();
  // pass 3: linear write-out; bucket of position p via binary search on excl
  for (int p = t; p < cend; p += 256) {
    int b = 0;
#pragma unroll
    for (int st = 256; st > 0; st >>= 1)
      if (b + st < NB_MAX && excl[b + st] <= p) b += st;
    rec[gdel[b] + p] = stage[p];
  }
}

__global__ __launch_bounds__(256) void csr_kernel(
    const unsigned* __restrict__ rec, const int* __restrict__ bbase,
    int* __restrict__ ptr, int* __restrict__ srt, int N, int NB, int E) {
  __shared__ int cnt[BW];
  __shared__ int s[256];
  int b = blockIdx.x, t = threadIdx.x;
  int rb0 = bbase[b], rb1 = bbase[b + 1];
  for (int i = t; i < BW; i += 256) cnt[i] = 0;
  __syncthreads();
  for (int j = rb0 + t; j < rb1; j += 256) atomicAdd(&cnt[rec[j] >> 20], 1);
  __syncthreads();
  int sum = 0;
#pragma unroll
  for (int j = 0; j < 8; ++j) sum += cnt[t * 8 + j];
  s[t] = sum;
  __syncthreads();
  for (int off = 1; off < 256; off <<= 1) {
    int x = (t >= off) ? s[t - off] : 0;
    __syncthreads();
    s[t] += x;
    __syncthreads();
  }
  int run = (t == 0) ? 0 : s[t - 1];
  int nb0 = b << BW_SHIFT;
#pragma unroll
  for (int j = 0; j < 8; ++j) {
    int idx = t * 8 + j;
    int c = cnt[idx];
    cnt[idx] = run;                       // becomes local cursor
    int node = nb0 + idx;
    if (node < N) ptr[node] = rb0 + run;
    run += c;
  }
  __syncthreads();
  for (int j = rb0 + t; j < rb1; j += 256) {
    unsigned r = rec[j];
    int off = atomicAdd(&cnt[r >> 20], 1);
    srt[rb0 + off] = (int)(r & 0xFFFFFu);
  }
  if (b == NB - 1 && t == 0) ptr[N] = E;
}

// ---- dense per-node kernels --------------------------------------------

// g[i,:] = (embed[x[i],:] @ W1) * dinv[i]
template <typename T>
__global__ __launch_bounds__(256) void embed_mm_kernel(
    const int* __restrict__ x, const float* __restrict__ embed,
    const float* __restrict__ W, const int* __restrict__ ptr,
    T* __restrict__ g, int n) {
  __shared__ float Ws[256];
  Ws[threadIdx.x] = W[threadIdx.x];
  __syncthreads();
  int i = blockIdx.x * 256 + threadIdx.x;
  if (i >= n) return;
  float dv = rsqrtf((float)(ptr[i + 1] - ptr[i]) + 1.0f);
  int row = x[i];
  float h[16];
  GIO<float>::load16(embed + (size_t)row * 16, h);
  float o[16];
#pragma unroll
  for (int j = 0; j < 16; ++j) o[j] = 0.f;
#pragma unroll
  for (int k = 0; k < 16; ++k) {
    float hk = h[k];
#pragma unroll
    for (int j = 0; j < 16; ++j) o[j] = fmaf(hk, Ws[k * 16 + j], o[j]);
  }
#pragma unroll
  for (int j = 0; j < 16; ++j) o[j] *= dv;
  GIO<T>::store16(g + (size_t)i * 16, o);
}

// 4 lanes/node, lane q owns feats [4q,4q+4). 4-way unrolled, two chains.
template <typename T>
__device__ __forceinline__ float4 gather_acc(
    const int* __restrict__ srt, const T* __restrict__ g,
    int d, int q, int p0, int p1) {
  const T* gq = g + q * 4;
  float4 acc0 = GIO<T>::loadv(g + (size_t)d * 16 + q * 4);  // self row
  float4 acc1 = make_float4(0.f, 0.f, 0.f, 0.f);
  int j = p0;
  for (; j + 4 <= p1; j += 4) {
    int s0 = srt[j], s1 = srt[j + 1], s2 = srt[j + 2], s3 = srt[j + 3];
    float4 r0 = GIO<T>::loadv(gq + (size_t)s0 * 16);
    float4 r1 = GIO<T>::loadv(gq + (size_t)s1 * 16);
    float4 r2 = GIO<T>::loadv(gq + (size_t)s2 * 16);
    float4 r3 = GIO<T>::loadv(gq + (size_t)s3 * 16);
    acc0 = add4(acc0, add4(r0, r2));
    acc1 = add4(acc1, add4(r1, r3));
  }
  for (; j < p1; ++j)
    acc1 = add4(acc1, GIO<T>::loadv(gq + (size_t)srt[j] * 16));
  return add4(acc0, acc1);
}

// layer-1 gather + finalize + fold layer-2 GEMM and fc head to scalars:
// qu[d] = dv * h . (W2 w_hi), qv[d] = dv * h . (W2 w_lo)
template <typename T>
__global__ __launch_bounds__(256) void gather_mm_kernel(
    const int* __restrict__ ptr, const int* __restrict__ srt,
    const T* __restrict__ g1, const float* __restrict__ W,
    const float* __restrict__ bias, const float* __restrict__ fcw,
    float2* __restrict__ quv, int n) {
  __shared__ float Ws[256];
  __shared__ float bs[16];
  __shared__ float cw[32];
  __shared__ float wu2[16];
  __shared__ float wv2[16];
  Ws[threadIdx.x] = W[threadIdx.x];
  if (threadIdx.x < 16) bs[threadIdx.x] = bias[threadIdx.x];
  if (threadIdx.x < 32) cw[threadIdx.x] = fcw[threadIdx.x];
  __syncthreads();
  if (threadIdx.x < 16) {
    float su = 0.f, sv = 0.f;
#pragma unroll
    for (int o = 0; o < 16; ++o) {
      float wk = Ws[threadIdx.x * 16 + o];
      su = fmaf(wk, cw[o], su);
      sv = fmaf(wk, cw[16 + o], sv);
    }
    wu2[threadIdx.x] = su;
    wv2[threadIdx.x] = sv;
  }
  __syncthreads();
  int t = blockIdx.x * 256 + threadIdx.x;
  int d = t >> 2;
  if (d >= n) return;
  int q = t & 3;
  int p0 = ptr[d], p1 = ptr[d + 1];
  float dv = rsqrtf((float)(p1 - p0) + 1.0f);
  float4 acc = gather_acc<T>(srt, g1, d, q, p0, p1);
  float4 b4 = *(const float4*)&bs[q * 4];
  float4 h = make_float4(fmaxf(fmaf(dv, acc.x, b4.x), 0.f),
                         fmaxf(fmaf(dv, acc.y, b4.y), 0.f),
                         fmaxf(fmaf(dv, acc.z, b4.z), 0.f),
                         fmaxf(fmaf(dv, acc.w, b4.w), 0.f));
  float4 uu = *(const float4*)&wu2[q * 4];
  float4 vv = *(const float4*)&wv2[q * 4];
  float pu = fmaf(h.x, uu.x, fmaf(h.y, uu.y, fmaf(h.z, uu.z, h.w * uu.w)));
  float pv = fmaf(h.x, vv.x, fmaf(h.y, vv.y, fmaf(h.z, vv.z, h.w * vv.w)));
  pu += __shfl_xor(pu, 1, 4); pu += __shfl_xor(pu, 2, 4);
  pv += __shfl_xor(pv, 1, 4); pv += __shfl_xor(pv, 2, 4);
  if (q == 0) quv[d] = make_float2(pu * dv, pv * dv);
}

// layer-2 gather on scalars: u[d] = dv*(qu[d]+sum qu[s]) + b2.w_hi; v likewise
__global__ __launch_bounds__(256) void gather_fin_scalar_kernel(
    const int* __restrict__ ptr, const int* __restrict__ srt,
    const float2* __restrict__ quv, const float* __restrict__ bias,
    const float* __restrict__ fcw, float* __restrict__ u,
    float* __restrict__ v, int n) {
  __shared__ float cu_s, cv_s;
  if (threadIdx.x == 0) {
    float cu = 0.f, cv = 0.f;
    for (int o = 0; o < 16; ++o) {
      float b = bias[o];
      cu = fmaf(b, fcw[o], cu);
      cv = fmaf(b, fcw[16 + o], cv);
    }
    cu_s = cu; cv_s = cv;
  }
  __syncthreads();
  int d = blockIdx.x * 256 + threadIdx.x;
  if (d >= n) return;
  int p0 = ptr[d], p1 = ptr[d + 1];
  float dv = rsqrtf((float)(p1 - p0) + 1.0f);
  float2 q0 = quv[d];
  float au0 = q0.x, av0 = q0.y, au1 = 0.f, av1 = 0.f;
  int j = p0;
  for (; j + 4 <= p1; j += 4) {
    int s0 = srt[j], s1 = srt[j + 1], s2 = srt[j + 2], s3 = srt[j + 3];
    float2 r0 = quv[s0], r1 = quv[s1], r2 = quv[s2], r3 = quv[s3];
    au0 += r0.x + r2.x; av0 += r0.y + r2.y;
    au1 += r1.x + r3.x; av1 += r1.y + r3.y;
  }
  for (; j < p1; ++j) {
    float2 r = quv[srt[j]];
    au1 += r.x; av1 += r.y;
  }
  u[d] = fmaf(dv, au0 + au1, cu_s);
  v[d] = fmaf(dv, av0 + av1, cv_s);
}

// out[e] = u[a] + v[b] + fc_b
__global__ __launch_bounds__(256) void predict_kernel(
    const int* __restrict__ eli, const float* __restrict__ u,
    const float* __restrict__ v, const float* __restrict__ fcb,
    float* __restrict__ out, int EL) {
  int e = blockIdx.x * 256 + threadIdx.x;
  if (e >= EL) return;
  int a = eli[e], b = eli[EL + e];
  out[e] = u[a] + v[b] + fcb[0];
}

static inline int cdiv(long long a, long long b) { return (int)((a + b - 1) / b); }

template <typename T>
static void run_pipeline(const int* x, const int* src, const int* dst,
                         const int* eli, const float* embed,
                         const float* W1, const float* b1,
                         const float* W2, const float* b2,
                         const float* fcw, const float* fcb, float* out,
                         int N, int E, int EL,
                         int* ptr, int* srt, T* bufA, T* bufB,
                         hipStream_t stream) {
  // aliasing: bufA = CSR scratch -> g1 -> u,v ; bufB = rec -> quv
  char* bA = (char*)bufA;
  int* bcnt  = (int*)bA;                 // [NB_MAX]
  int* bbase = (int*)(bA + 4096);        // [NB+1]
  int* bcur  = (int*)(bA + 8192);        // [NB_MAX*16] padded cursors
  unsigned* rec = (unsigned*)bufB;       // [E]
  float2* quv = (float2*)bufB;           // [N] (after csr consumes rec)
  float* u = (float*)bA;                 // [N] (after gather_mm consumes g1)
  float* v = u + N;                      // [N]

  const int B = 256;
  const int NB = cdiv(N, BW);

  hipMemsetAsync(bcnt, 0, NB_MAX * 4, stream);
  bhist_kernel<<<cdiv(E, 8192), B, 0, stream>>>(dst, bcnt, E);
  bscan_kernel<<<1, 512, 0, stream>>>(bcnt, bbase, bcur, NB);
  bin_kernel<<<cdiv(E, CHUNK), B, 0, stream>>>(src, dst, bcur, rec, E);
  csr_kernel<<<NB, B, 0, stream>>>(rec, bbase, ptr, srt, N, NB, E);

  embed_mm_kernel<T><<<cdiv(N, B), B, 0, stream>>>(x, embed, W1, ptr, bufA, N);
  gather_mm_kernel<T><<<cdiv((long long)N * 4, B), B, 0, stream>>>(
      ptr, srt, bufA, W2, b1, fcw, quv, N);
  gather_fin_scalar_kernel<<<cdiv(N, B), B, 0, stream>>>(
      ptr, srt, quv, b2, fcw, u, v, N);
  predict_kernel<<<cdiv(EL, B), B, 0, stream>>>(eli, u, v, fcb, out, EL);
}

extern "C" void kernel_launch(void* const* d_in, const int* in_sizes, int n_in,
                              void* d_out, int out_size, void* d_ws, size_t ws_size,
                              hipStream_t stream) {
  const int*   x     = (const int*)d_in[0];
  const int*   ei    = (const int*)d_in[1];   // [2,E]
  const int*   eli   = (const int*)d_in[2];   // [2,EL]
  const float* embed = (const float*)d_in[3];
  const float* W1    = (const float*)d_in[4];
  const float* b1    = (const float*)d_in[5];
  const float* W2    = (const float*)d_in[6];
  const float* b2    = (const float*)d_in[7];
  const float* fcw   = (const float*)d_in[8];
  const float* fcb   = (const float*)d_in[9];
  float* out = (float*)d_out;

  const int N  = in_sizes[0];
  const int E  = in_sizes[1] / 2;
  const int EL = in_sizes[2] / 2;
  const int* src = ei;
  const int* dst = ei + E;

  size_t ptrB = ((size_t)(N + 1) * 4 + 255) & ~(size_t)255;
  size_t srtB = ((size_t)E * 4 + 255) & ~(size_t)255;
  size_t bufF = ((size_t)N * 16 * sizeof(float) + 255) & ~(size_t)255;
  size_t bufH = ((size_t)N * 16 * sizeof(bf16) + 255) & ~(size_t)255;

  char* w = (char*)d_ws;
  int* ptr = (int*)w;
  int* srt = (int*)(w + ptrB);
  char* bA = w + ptrB + srtB;

  if (ws_size >= ptrB + srtB + 2 * bufF) {
    run_pipeline<float>(x, src, dst, eli, embed, W1, b1, W2, b2, fcw, fcb, out,
                        N, E, EL, ptr, srt, (float*)bA, (float*)(bA + bufF), stream);
  } else {
    run_pipeline<bf16>(x, src, dst, eli, embed, W1, b1, W2, b2, fcw, fcb, out,
                       N, E, EL, ptr, srt, (bf16*)bA, (bf16*)(bA + bufH), stream);
  }
}

// Round 6
// 488.128 us; speedup vs baseline: 2.4484x; 1.0422x over previous
//
#include <hip/hip_runtime.h>
#include <hip/hip_bf16.h>

// GCN link-prediction, N=1M, D=16, E=5M, EL=2M.
// R6: g1 table stored in bf16 (32B rows) -> random-gather table 64->32MB:
// fewer line fills, higher L2 hit rate, halved embed_mm writes. quv/u/v
// stay fp32 (precision headroom). Pipeline otherwise as R5:
//   CSR build (bhist/bscan/LDS-staged bin/csr) -> embed_mm(bf16 out) ->
//   gather_mm (4-lane gather + W1-finalize + W2*fc fold -> quv scalars) ->
//   gather_fin_scalar -> predict.

typedef __hip_bfloat16 bf16;

#define BW_SHIFT 11            // bucket node-width = 2048 (needs N <= 1<<20)
#define BW (1 << BW_SHIFT)
#define NB_MAX 512
#define CHUNK 16384            // edges per bin block (64KB LDS stage)

__device__ __forceinline__ float bf2f(unsigned short s) {
  unsigned u = ((unsigned)s) << 16; float f; __builtin_memcpy(&f, &u, 4); return f;
}
__device__ __forceinline__ unsigned short f2bf(float f) {
  bf16 b = __float2bfloat16(f); unsigned short s; __builtin_memcpy(&s, &b, 2); return s;
}
__device__ __forceinline__ float4 add4(float4 a, float4 b) {
  return make_float4(a.x + b.x, a.y + b.y, a.z + b.z, a.w + b.w);
}

// lane q of 4 owns feats [4q,4q+4) -> 8B ushort4 load from a 32B row
__device__ __forceinline__ float4 loadv_bf(const bf16* p) {
  ushort4 u = *(const ushort4*)p;
  return make_float4(bf2f(u.x), bf2f(u.y), bf2f(u.z), bf2f(u.w));
}
__device__ __forceinline__ void store16_bf(bf16* p, const float* h) {
  unsigned short t[16];
#pragma unroll
  for (int j = 0; j < 16; ++j) t[j] = f2bf(h[j]);
  uint4 r0, r1;
  __builtin_memcpy(&r0, &t[0], 16);
  __builtin_memcpy(&r1, &t[8], 16);
  uint4* q = (uint4*)p;
  q[0] = r0; q[1] = r1;
}

// ---- CSR build ----------------------------------------------------------

__global__ __launch_bounds__(256) void bhist_kernel(
    const int* __restrict__ dst, int* __restrict__ bcnt, int E) {
  __shared__ int h[NB_MAX];
  for (int i = threadIdx.x; i < NB_MAX; i += 256) h[i] = 0;
  __syncthreads();
  int cb = blockIdx.x * 8192;
#pragma unroll 4
  for (int k = 0; k < 32; ++k) {
    int e = cb + k * 256 + threadIdx.x;
    if (e < E) atomicAdd(&h[dst[e] >> BW_SHIFT], 1);
  }
  __syncthreads();
  for (int i = threadIdx.x; i < NB_MAX; i += 256) {
    int c = h[i];
    if (c) atomicAdd(&bcnt[i], c);
  }
}

__global__ __launch_bounds__(512) void bscan_kernel(
    const int* __restrict__ bcnt, int* __restrict__ bbase,
    int* __restrict__ bcur, int NB) {
  __shared__ int s[512];
  int t = threadIdx.x;
  int v = (t < NB) ? bcnt[t] : 0;
  s[t] = v;
  __syncthreads();
  for (int off = 1; off < 512; off <<= 1) {
    int x = (t >= off) ? s[t - off] : 0;
    __syncthreads();
    s[t] += x;
    __syncthreads();
  }
  int excl = (t == 0) ? 0 : s[t - 1];
  if (t < NB) { bbase[t] = excl; bcur[t * 16] = excl; }
  if (t == NB - 1) bbase[NB] = excl + v;
}

// bin edges into bucket runs as packed records (ldst<<20 | src), LDS-staged:
// per-chunk hist -> scan -> LDS scatter (bucket-sorted) -> linear coalesced
// global write via binary-searched bucket delta.
__global__ __launch_bounds__(256) void bin_kernel(
    const int* __restrict__ src, const int* __restrict__ dst,
    int* __restrict__ bcur, unsigned* __restrict__ rec, int E) {
  __shared__ int hist[NB_MAX];
  __shared__ int excl[NB_MAX];
  __shared__ int gdel[NB_MAX];
  __shared__ int cur[NB_MAX];
  __shared__ int s[256];
  __shared__ unsigned stage[CHUNK];
  int t = threadIdx.x;
  hist[t] = 0; hist[t + 256] = 0;
  __syncthreads();
  int cb = blockIdx.x * CHUNK;
  int cend = E - cb; if (cend > CHUNK) cend = CHUNK;
  // pass 1: count
#pragma unroll 4
  for (int k = 0; k < CHUNK / 256; ++k) {
    int i = k * 256 + t;
    if (i < cend) atomicAdd(&hist[dst[cb + i] >> BW_SHIFT], 1);
  }
  __syncthreads();
  // scan 512 entries with 256 threads
  int a0 = hist[2 * t], a1 = hist[2 * t + 1];
  s[t] = a0 + a1;
  __syncthreads();
  for (int off = 1; off < 256; off <<= 1) {
    int x = (t >= off) ? s[t - off] : 0;
    __syncthreads();
    s[t] += x;
    __syncthreads();
  }
  int e0 = (t == 0) ? 0 : s[t - 1];
  excl[2 * t] = e0; excl[2 * t + 1] = e0 + a0;
  cur[2 * t] = e0;  cur[2 * t + 1] = e0 + a0;
  if (a0) gdel[2 * t]     = atomicAdd(&bcur[(2 * t) * 16], a0)     - e0;
  if (a1) gdel[2 * t + 1] = atomicAdd(&bcur[(2 * t + 1) * 16], a1) - (e0 + a0);
  __syncthreads();
  // pass 2: scatter records into LDS, bucket-sorted
#pragma unroll 4
  for (int k = 0; k < CHUNK / 256; ++k) {
    int i = k * 256 + t;
    if (i < cend) {
      int d = dst[cb + i];
      int b = d >> BW_SHIFT;
      unsigned r = ((unsigned)(d & (BW - 1)) << 20) | (unsigned)src[cb + i];
      int off = atomicAdd(&cur[b], 1);
      stage[off] = r;
    }
  }
  __syncthreads();
  // pass 3: linear write-out; bucket of position p via binary search on excl
  for (int p = t; p < cend; p += 256) {
    int b = 0;
#pragma unroll
    for (int st = 256; st > 0; st >>= 1)
      if (b + st < NB_MAX && excl[b + st] <= p) b += st;
    rec[gdel[b] + p] = stage[p];
  }
}

__global__ __launch_bounds__(256) void csr_kernel(
    const unsigned* __restrict__ rec, const int* __restrict__ bbase,
    int* __restrict__ ptr, int* __restrict__ srt, int N, int NB, int E) {
  __shared__ int cnt[BW];
  __shared__ int s[256];
  int b = blockIdx.x, t = threadIdx.x;
  int rb0 = bbase[b], rb1 = bbase[b + 1];
  for (int i = t; i < BW; i += 256) cnt[i] = 0;
  __syncthreads();
  for (int j = rb0 + t; j < rb1; j += 256) atomicAdd(&cnt[rec[j] >> 20], 1);
  __syncthreads();
  int sum = 0;
#pragma unroll
  for (int j = 0; j < 8; ++j) sum += cnt[t * 8 + j];
  s[t] = sum;
  __syncthreads();
  for (int off = 1; off < 256; off <<= 1) {
    int x = (t >= off) ? s[t - off] : 0;
    __syncthreads();
    s[t] += x;
    __syncthreads();
  }
  int run = (t == 0) ? 0 : s[t - 1];
  int nb0 = b << BW_SHIFT;
#pragma unroll
  for (int j = 0; j < 8; ++j) {
    int idx = t * 8 + j;
    int c = cnt[idx];
    cnt[idx] = run;                       // becomes local cursor
    int node = nb0 + idx;
    if (node < N) ptr[node] = rb0 + run;
    run += c;
  }
  __syncthreads();
  for (int j = rb0 + t; j < rb1; j += 256) {
    unsigned r = rec[j];
    int off = atomicAdd(&cnt[r >> 20], 1);
    srt[rb0 + off] = (int)(r & 0xFFFFFu);
  }
  if (b == NB - 1 && t == 0) ptr[N] = E;
}

// ---- dense per-node kernels --------------------------------------------

// g[i,:] = (embed[x[i],:] @ W1) * dinv[i]  -> bf16
__global__ __launch_bounds__(256) void embed_mm_kernel(
    const int* __restrict__ x, const float* __restrict__ embed,
    const float* __restrict__ W, const int* __restrict__ ptr,
    bf16* __restrict__ g, int n) {
  __shared__ float Ws[256];
  Ws[threadIdx.x] = W[threadIdx.x];
  __syncthreads();
  int i = blockIdx.x * 256 + threadIdx.x;
  if (i >= n) return;
  float dv = rsqrtf((float)(ptr[i + 1] - ptr[i]) + 1.0f);
  int row = x[i];
  const float4* hp = (const float4*)(embed + (size_t)row * 16);
  float4 ha = hp[0], hb = hp[1], hc = hp[2], hd = hp[3];
  float h[16] = {ha.x,ha.y,ha.z,ha.w, hb.x,hb.y,hb.z,hb.w,
                 hc.x,hc.y,hc.z,hc.w, hd.x,hd.y,hd.z,hd.w};
  float o[16];
#pragma unroll
  for (int j = 0; j < 16; ++j) o[j] = 0.f;
#pragma unroll
  for (int k = 0; k < 16; ++k) {
    float hk = h[k];
#pragma unroll
    for (int j = 0; j < 16; ++j) o[j] = fmaf(hk, Ws[k * 16 + j], o[j]);
  }
#pragma unroll
  for (int j = 0; j < 16; ++j) o[j] *= dv;
  store16_bf(g + (size_t)i * 16, o);
}

// 4 lanes/node, lane q owns feats [4q,4q+4) (8B bf16 loads).
// 4-way unrolled, two independent chains.
__device__ __forceinline__ float4 gather_acc_bf(
    const int* __restrict__ srt, const bf16* __restrict__ g,
    int d, int q, int p0, int p1) {
  const bf16* gq = g + q * 4;
  float4 acc0 = loadv_bf(g + (size_t)d * 16 + q * 4);  // self row
  float4 acc1 = make_float4(0.f, 0.f, 0.f, 0.f);
  int j = p0;
  for (; j + 4 <= p1; j += 4) {
    int s0 = srt[j], s1 = srt[j + 1], s2 = srt[j + 2], s3 = srt[j + 3];
    float4 r0 = loadv_bf(gq + (size_t)s0 * 16);
    float4 r1 = loadv_bf(gq + (size_t)s1 * 16);
    float4 r2 = loadv_bf(gq + (size_t)s2 * 16);
    float4 r3 = loadv_bf(gq + (size_t)s3 * 16);
    acc0 = add4(acc0, add4(r0, r2));
    acc1 = add4(acc1, add4(r1, r3));
  }
  for (; j < p1; ++j)
    acc1 = add4(acc1, loadv_bf(gq + (size_t)srt[j] * 16));
  return add4(acc0, acc1);
}

// layer-1 gather + finalize + fold layer-2 GEMM and fc head to scalars:
// qu[d] = dv * h . (W2 w_hi), qv[d] = dv * h . (W2 w_lo)
__global__ __launch_bounds__(256) void gather_mm_kernel(
    const int* __restrict__ ptr, const int* __restrict__ srt,
    const bf16* __restrict__ g1, const float* __restrict__ W,
    const float* __restrict__ bias, const float* __restrict__ fcw,
    float2* __restrict__ quv, int n) {
  __shared__ float Ws[256];
  __shared__ float bs[16];
  __shared__ float cw[32];
  __shared__ float wu2[16];
  __shared__ float wv2[16];
  Ws[threadIdx.x] = W[threadIdx.x];
  if (threadIdx.x < 16) bs[threadIdx.x] = bias[threadIdx.x];
  if (threadIdx.x < 32) cw[threadIdx.x] = fcw[threadIdx.x];
  __syncthreads();
  if (threadIdx.x < 16) {
    float su = 0.f, sv = 0.f;
#pragma unroll
    for (int o = 0; o < 16; ++o) {
      float wk = Ws[threadIdx.x * 16 + o];
      su = fmaf(wk, cw[o], su);
      sv = fmaf(wk, cw[16 + o], sv);
    }
    wu2[threadIdx.x] = su;
    wv2[threadIdx.x] = sv;
  }
  __syncthreads();
  int t = blockIdx.x * 256 + threadIdx.x;
  int d = t >> 2;
  if (d >= n) return;
  int q = t & 3;
  int p0 = ptr[d], p1 = ptr[d + 1];
  float dv = rsqrtf((float)(p1 - p0) + 1.0f);
  float4 acc = gather_acc_bf(srt, g1, d, q, p0, p1);
  float4 b4 = *(const float4*)&bs[q * 4];
  float4 h = make_float4(fmaxf(fmaf(dv, acc.x, b4.x), 0.f),
                         fmaxf(fmaf(dv, acc.y, b4.y), 0.f),
                         fmaxf(fmaf(dv, acc.z, b4.z), 0.f),
                         fmaxf(fmaf(dv, acc.w, b4.w), 0.f));
  float4 uu = *(const float4*)&wu2[q * 4];
  float4 vv = *(const float4*)&wv2[q * 4];
  float pu = fmaf(h.x, uu.x, fmaf(h.y, uu.y, fmaf(h.z, uu.z, h.w * uu.w)));
  float pv = fmaf(h.x, vv.x, fmaf(h.y, vv.y, fmaf(h.z, vv.z, h.w * vv.w)));
  pu += __shfl_xor(pu, 1, 4); pu += __shfl_xor(pu, 2, 4);
  pv += __shfl_xor(pv, 1, 4); pv += __shfl_xor(pv, 2, 4);
  if (q == 0) quv[d] = make_float2(pu * dv, pv * dv);
}

// layer-2 gather on scalars: u[d] = dv*(qu[d]+sum qu[s]) + b2.w_hi; v likewise
__global__ __launch_bounds__(256) void gather_fin_scalar_kernel(
    const int* __restrict__ ptr, const int* __restrict__ srt,
    const float2* __restrict__ quv, const float* __restrict__ bias,
    const float* __restrict__ fcw, float* __restrict__ u,
    float* __restrict__ v, int n) {
  __shared__ float cu_s, cv_s;
  if (threadIdx.x == 0) {
    float cu = 0.f, cv = 0.f;
    for (int o = 0; o < 16; ++o) {
      float b = bias[o];
      cu = fmaf(b, fcw[o], cu);
      cv = fmaf(b, fcw[16 + o], cv);
    }
    cu_s = cu; cv_s = cv;
  }
  __syncthreads();
  int d = blockIdx.x * 256 + threadIdx.x;
  if (d >= n) return;
  int p0 = ptr[d], p1 = ptr[d + 1];
  float dv = rsqrtf((float)(p1 - p0) + 1.0f);
  float2 q0 = quv[d];
  float au0 = q0.x, av0 = q0.y, au1 = 0.f, av1 = 0.f;
  int j = p0;
  for (; j + 4 <= p1; j += 4) {
    int s0 = srt[j], s1 = srt[j + 1], s2 = srt[j + 2], s3 = srt[j + 3];
    float2 r0 = quv[s0], r1 = quv[s1], r2 = quv[s2], r3 = quv[s3];
    au0 += r0.x + r2.x; av0 += r0.y + r2.y;
    au1 += r1.x + r3.x; av1 += r1.y + r3.y;
  }
  for (; j < p1; ++j) {
    float2 r = quv[srt[j]];
    au1 += r.x; av1 += r.y;
  }
  u[d] = fmaf(dv, au0 + au1, cu_s);
  v[d] = fmaf(dv, av0 + av1, cv_s);
}

// out[e] = u[a] + v[b] + fc_b
__global__ __launch_bounds__(256) void predict_kernel(
    const int* __restrict__ eli, const float* __restrict__ u,
    const float* __restrict__ v, const float* __restrict__ fcb,
    float* __restrict__ out, int EL) {
  int e = blockIdx.x * 256 + threadIdx.x;
  if (e >= EL) return;
  int a = eli[e], b = eli[EL + e];
  out[e] = u[a] + v[b] + fcb[0];
}

static inline int cdiv(long long a, long long b) { return (int)((a + b - 1) / b); }

extern "C" void kernel_launch(void* const* d_in, const int* in_sizes, int n_in,
                              void* d_out, int out_size, void* d_ws, size_t ws_size,
                              hipStream_t stream) {
  const int*   x     = (const int*)d_in[0];
  const int*   ei    = (const int*)d_in[1];   // [2,E]
  const int*   eli   = (const int*)d_in[2];   // [2,EL]
  const float* embed = (const float*)d_in[3];
  const float* W1    = (const float*)d_in[4];
  const float* b1    = (const float*)d_in[5];
  const float* W2    = (const float*)d_in[6];
  const float* b2    = (const float*)d_in[7];
  const float* fcw   = (const float*)d_in[8];
  const float* fcb   = (const float*)d_in[9];
  float* out = (float*)d_out;

  const int N  = in_sizes[0];
  const int E  = in_sizes[1] / 2;
  const int EL = in_sizes[2] / 2;
  const int* src = ei;
  const int* dst = ei + E;

  // ws layout: ptr | srt | bufA (g1 bf16 32MB; CSR scratch early, u/v late)
  //            | bufB (rec 20MB -> quv 8MB)
  size_t ptrB = ((size_t)(N + 1) * 4 + 255) & ~(size_t)255;
  size_t srtB = ((size_t)E * 4 + 255) & ~(size_t)255;
  size_t bufAB = ((size_t)N * 16 * sizeof(bf16) + 255) & ~(size_t)255;

  char* w = (char*)d_ws;
  int* ptr = (int*)w;
  int* srt = (int*)(w + ptrB);
  char* bA = w + ptrB + srtB;
  char* bB = bA + bufAB;

  // aliasing: bufA = CSR scratch -> g1 -> u,v ; bufB = rec -> quv
  int* bcnt  = (int*)bA;                 // [NB_MAX]
  int* bbase = (int*)(bA + 4096);        // [NB+1]
  int* bcur  = (int*)(bA + 8192);        // [NB_MAX*16] padded cursors
  bf16* g1 = (bf16*)bA;
  unsigned* rec = (unsigned*)bB;         // [E]
  float2* quv = (float2*)bB;             // [N] (after csr consumes rec)
  float* u = (float*)bA;                 // [N] (after gather_mm consumes g1)
  float* v = u + N;                      // [N]

  const int B = 256;
  const int NB = cdiv(N, BW);

  hipMemsetAsync(bcnt, 0, NB_MAX * 4, stream);
  bhist_kernel<<<cdiv(E, 8192), B, 0, stream>>>(dst, bcnt, E);
  bscan_kernel<<<1, 512, 0, stream>>>(bcnt, bbase, bcur, NB);
  bin_kernel<<<cdiv(E, CHUNK), B, 0, stream>>>(src, dst, bcur, rec, E);
  csr_kernel<<<NB, B, 0, stream>>>(rec, bbase, ptr, srt, N, NB, E);

  embed_mm_kernel<<<cdiv(N, B), B, 0, stream>>>(x, embed, W1, ptr, g1, N);
  gather_mm_kernel<<<cdiv((long long)N * 4, B), B, 0, stream>>>(
      ptr, srt, g1, W2, b1, fcw, quv, N);
  gather_fin_scalar_kernel<<<cdiv(N, B), B, 0, stream>>>(
      ptr, srt, quv, b2, fcw, u, v, N);
  predict_kernel<<<cdiv(EL, B), B, 0, stream>>>(eli, u, v, fcb, out, EL);
}